// Round 1
// baseline (3464.160 us; speedup 1.0000x reference)
//
#include <hip/hip_runtime.h>
#include <hip/hip_bf16.h>
#include <cstdint>
#include <cstddef>

#define NB 64      // batch
#define DD 256     // model dim
#define NN 625     // tokens = 25*25
#define NH 8       // heads
#define DH 32      // head dim
#define N3 768     // 3*DD

// ---------------------------------------------------------------------------
// Kernel 0: transpose-gather the relative-position bias into (h, j, i) layout
// so the attention inner loop reads it coalesced over i (lane dim).
// ---------------------------------------------------------------------------
__global__ __launch_bounds__(256)
void biasT_kernel(const int* __restrict__ rel, const float* __restrict__ table,
                  float* __restrict__ biasT)
{
    __shared__ int sidx[64][65];
    const int i0 = blockIdx.x * 64;
    const int j0 = blockIdx.y * 64;
    const int tid = threadIdx.x;
    #pragma unroll
    for (int r = 0; r < 16; ++r) {
        const int flat = r * 256 + tid;
        const int ii = flat >> 6, jj = flat & 63;
        const int iG = i0 + ii, jG = j0 + jj;
        sidx[ii][jj] = (iG < NN && jG < NN) ? rel[(size_t)iG * NN + jG] : 0;
    }
    __syncthreads();
    for (int h = 0; h < NH; ++h) {
        #pragma unroll
        for (int r = 0; r < 16; ++r) {
            const int flat = r * 256 + tid;
            const int jj = flat >> 6, ii = flat & 63;   // ii fast -> coalesced write
            const int iG = i0 + ii, jG = j0 + jj;
            if (iG < NN && jG < NN)
                biasT[((size_t)h * NN + jG) * NN + iG] = table[sidx[ii][jj] * NH + h];
        }
    }
}

// ---------------------------------------------------------------------------
// Kernel 1: QKV projection.  qkv[b][i][j] = sum_d x[b][d][i] * w_qkv[d][j]
// x is (b, d, n) so A is stored transposed (good: contiguous in i).
// Output scattered to Q/K/V in (b, h, n, 32) layout; Q pre-scaled by dh^-0.5.
// ---------------------------------------------------------------------------
__global__ __launch_bounds__(256)
void qkv_kernel(const float* __restrict__ x, const float* __restrict__ w,
                float* __restrict__ Q, float* __restrict__ K, float* __restrict__ V)
{
    __shared__ float Xs[16][64];   // [kk][ii]
    __shared__ float Ws[16][64];   // [kk][jj]
    const int b  = blockIdx.z;
    const int i0 = blockIdx.x * 64;
    const int j0 = blockIdx.y * 64;
    const int tid = threadIdx.x;
    const int ti = tid >> 4;       // 0..15  (i group)
    const int tj = tid & 15;       // 0..15  (j group)
    const float* xb = x + (size_t)b * DD * NN;

    float acc[4][4];
    #pragma unroll
    for (int a = 0; a < 4; ++a)
        #pragma unroll
        for (int c = 0; c < 4; ++c) acc[a][c] = 0.f;

    for (int k0 = 0; k0 < DD; k0 += 16) {
        // stage X tile: scalar coalesced loads (row stride 625 floats -> float4
        // would be misaligned).  lanes cover ii contiguously.
        {
            const int ii = tid & 63;
            const int kb = tid >> 6;           // 0..3
            const int i  = i0 + ii;
            #pragma unroll
            for (int r = 0; r < 4; ++r) {
                const int kk = kb + r * 4;
                Xs[kk][ii] = (i < NN) ? xb[(size_t)(k0 + kk) * NN + i] : 0.f;
            }
        }
        {
            const int kk  = tid >> 4;
            const int jj4 = (tid & 15) * 4;    // w row stride 768: float4 OK
            *(float4*)&Ws[kk][jj4] = *(const float4*)&w[(size_t)(k0 + kk) * N3 + j0 + jj4];
        }
        __syncthreads();
        #pragma unroll
        for (int kk = 0; kk < 16; ++kk) {
            float av[4], bv[4];
            *(float4*)av = *(const float4*)&Xs[kk][ti * 4];
            *(float4*)bv = *(const float4*)&Ws[kk][tj * 4];
            #pragma unroll
            for (int a = 0; a < 4; ++a)
                #pragma unroll
                for (int c = 0; c < 4; ++c)
                    acc[a][c] += av[a] * bv[c];
        }
        __syncthreads();
    }

    // scatter: 4 consecutive j columns stay within one head (4 | 32)
    const int jb = j0 + tj * 4;
    const int t  = jb >> 8;            // 0=q 1=k 2=v
    const int h  = (jb & 255) >> 5;
    const int cb = jb & 31;
    float* dstBase = (t == 0) ? Q : (t == 1) ? K : V;
    const float mul = (t == 0) ? 0.17677669529663687f : 1.f;   // 32^-0.5
    #pragma unroll
    for (int a = 0; a < 4; ++a) {
        const int i = i0 + ti * 4 + a;
        if (i < NN) {
            float4 v;
            v.x = acc[a][0] * mul; v.y = acc[a][1] * mul;
            v.z = acc[a][2] * mul; v.w = acc[a][3] * mul;
            *(float4*)&dstBase[(((size_t)b * NH + h) * NN + i) * DH + cb] = v;
        }
    }
}

// ---------------------------------------------------------------------------
// Kernel 2: flash-style attention.  One wave per 64 query rows of one (b,h).
// Q row, score tile, and output accumulator in registers (static indices);
// K/V 32x32 tiles in LDS read as broadcast ds_read_b128 (conflict-free).
// ---------------------------------------------------------------------------
__global__ __launch_bounds__(64)
void attn_kernel(const float* __restrict__ Q, const float* __restrict__ K,
                 const float* __restrict__ V, const float* __restrict__ biasT,
                 float* __restrict__ AO)
{
    __shared__ float Ks[32][32];
    __shared__ float Vs[32][32];
    const int b  = blockIdx.z;
    const int h  = blockIdx.y;
    const int i0 = blockIdx.x * 64;
    const int lane = threadIdx.x;
    const int i = i0 + lane;
    const bool valid = (i < NN);
    const int ic = valid ? i : (NN - 1);

    const size_t headOff = ((size_t)b * NH + h) * NN * DH;
    const float* qrow = Q + headOff + (size_t)ic * DH;
    const float* Kb = K + headOff;
    const float* Vb = V + headOff;
    const float* bh = biasT + (size_t)h * NN * NN;

    float q[DH];
    #pragma unroll
    for (int c = 0; c < DH; c += 4) *(float4*)&q[c] = *(const float4*)&qrow[c];

    float acc[DH];
    #pragma unroll
    for (int c = 0; c < DH; ++c) acc[c] = 0.f;
    float m = -1e30f, l = 0.f;

    for (int jt = 0; jt < NN; jt += 32) {
        const bool full = (jt + 32 <= NN);
        // stage K/V tile: 32x32 floats each; lane loads 4 float4 per matrix
        #pragma unroll
        for (int r = 0; r < 4; ++r) {
            const int flat = r * 256 + lane * 4;
            const int j = flat >> 5, c = flat & 31;
            const int jj = jt + j;
            float4 kv, vv;
            if (full || jj < NN) {
                kv = *(const float4*)&Kb[(size_t)jj * DH + c];
                vv = *(const float4*)&Vb[(size_t)jj * DH + c];
            } else {
                kv = make_float4(0.f, 0.f, 0.f, 0.f);
                vv = make_float4(0.f, 0.f, 0.f, 0.f);
            }
            *(float4*)&Ks[j][c] = kv;
            *(float4*)&Vs[j][c] = vv;
        }
        __syncthreads();

        float s[32];
        #pragma unroll
        for (int j = 0; j < 32; ++j) {
            float sum = 0.f;
            #pragma unroll
            for (int c4 = 0; c4 < 8; ++c4) {
                const float4 kv = *(const float4*)&Ks[j][c4 * 4];
                sum += q[c4*4+0]*kv.x + q[c4*4+1]*kv.y + q[c4*4+2]*kv.z + q[c4*4+3]*kv.w;
            }
            const int jj = jt + j;
            s[j] = (full || jj < NN) ? (sum + bh[(size_t)jj * NN + ic]) : -1e30f;
        }
        float tmax = s[0];
        #pragma unroll
        for (int j = 1; j < 32; ++j) tmax = fmaxf(tmax, s[j]);
        const float mnew = fmaxf(m, tmax);
        const float corr = __expf(m - mnew);
        l *= corr;
        #pragma unroll
        for (int c = 0; c < DH; ++c) acc[c] *= corr;
        #pragma unroll
        for (int j = 0; j < 32; ++j) {
            const float p = __expf(s[j] - mnew);
            l += p;
            #pragma unroll
            for (int c4 = 0; c4 < 8; ++c4) {
                const float4 vv = *(const float4*)&Vs[j][c4 * 4];
                acc[c4*4+0] += p * vv.x; acc[c4*4+1] += p * vv.y;
                acc[c4*4+2] += p * vv.z; acc[c4*4+3] += p * vv.w;
            }
        }
        m = mnew;
        __syncthreads();
    }

    if (valid) {
        const float invl = 1.f / l;
        float* dst = AO + ((size_t)b * NN + i) * DD + h * DH;
        #pragma unroll
        for (int c = 0; c < DH; c += 4) {
            float4 v;
            v.x = acc[c]*invl; v.y = acc[c+1]*invl;
            v.z = acc[c+2]*invl; v.w = acc[c+3]*invl;
            *(float4*)&dst[c] = v;
        }
    }
}

// ---------------------------------------------------------------------------
// Kernel 3: output projection + transpose.  out[b][j][i] = sum_d AO[b][i][d]*W[d][j]
// ---------------------------------------------------------------------------
__global__ __launch_bounds__(256)
void outproj_kernel(const float* __restrict__ A, const float* __restrict__ W,
                    float* __restrict__ out)
{
    __shared__ float As[16][68];   // [kk][ii], pad 68 keeps 16B align + 2-way banks
    __shared__ float Ws2[16][64];  // [kk][jj]
    const int b  = blockIdx.z;
    const int i0 = blockIdx.x * 64;
    const int j0 = blockIdx.y * 64;
    const int tid = threadIdx.x;
    const int ti = tid & 15;       // fast: i  (store coalescing)
    const int tj = tid >> 4;       // slow: j
    const float* Ab = A + (size_t)b * NN * DD;

    float acc[4][4];
    #pragma unroll
    for (int a = 0; a < 4; ++a)
        #pragma unroll
        for (int c = 0; c < 4; ++c) acc[a][c] = 0.f;

    for (int k0 = 0; k0 < DD; k0 += 16) {
        {
            const int ii = tid >> 2;            // 0..63
            const int kq = (tid & 3) * 4;       // 0,4,8,12
            const int i  = i0 + ii;
            float4 v = make_float4(0.f, 0.f, 0.f, 0.f);
            if (i < NN) v = *(const float4*)&Ab[(size_t)i * DD + k0 + kq];
            As[kq+0][ii] = v.x; As[kq+1][ii] = v.y;
            As[kq+2][ii] = v.z; As[kq+3][ii] = v.w;
        }
        {
            const int kk  = tid >> 4;
            const int jj4 = (tid & 15) * 4;
            *(float4*)&Ws2[kk][jj4] = *(const float4*)&W[(size_t)(k0 + kk) * DD + j0 + jj4];
        }
        __syncthreads();
        #pragma unroll
        for (int kk = 0; kk < 16; ++kk) {
            float av[4], bv[4];
            *(float4*)av = *(const float4*)&As[kk][ti * 4];
            *(float4*)bv = *(const float4*)&Ws2[kk][tj * 4];
            #pragma unroll
            for (int a = 0; a < 4; ++a)
                #pragma unroll
                for (int c = 0; c < 4; ++c)
                    acc[a][c] += av[a] * bv[c];
        }
        __syncthreads();
    }

    // transposed store; out row stride 625 floats (odd) -> scalar stores
    const int ibase = i0 + ti * 4;
    #pragma unroll
    for (int qj = 0; qj < 4; ++qj) {
        const int j = j0 + tj * 4 + qj;
        float* dst = out + ((size_t)b * DD + j) * NN;
        #pragma unroll
        for (int a = 0; a < 4; ++a)
            if (ibase + a < NN) dst[ibase + a] = acc[a][qj];
    }
}

// ---------------------------------------------------------------------------
extern "C" void kernel_launch(void* const* d_in, const int* in_sizes, int n_in,
                              void* d_out, int out_size, void* d_ws, size_t ws_size,
                              hipStream_t stream)
{
    (void)in_sizes; (void)n_in; (void)out_size; (void)ws_size;
    const float* x     = (const float*)d_in[0];
    const float* w_qkv = (const float*)d_in[1];
    const float* w_out = (const float*)d_in[2];
    const float* table = (const float*)d_in[3];
    const int*   rel   = (const int*)d_in[4];
    float* out = (float*)d_out;

    float* ws = (float*)d_ws;
    const size_t szQ = (size_t)NB * NH * NN * DH;   // 10,240,000 floats
    float* Q  = ws;
    float* K  = Q + szQ;
    float* V  = K + szQ;
    float* AO = V + szQ;                            // (b, n, d) = szQ floats
    float* BT = AO + szQ;                           // (h, j, i) = 3,125,000 floats

    biasT_kernel  <<<dim3(10, 10, 1),  256, 0, stream>>>(rel, table, BT);
    qkv_kernel    <<<dim3(10, 12, NB), 256, 0, stream>>>(x, w_qkv, Q, K, V);
    attn_kernel   <<<dim3(10, NH, NB), 64,  0, stream>>>(Q, K, V, BT, AO);
    outproj_kernel<<<dim3(10, 4,  NB), 256, 0, stream>>>(AO, w_out, out);
}